// Round 3
// baseline (1971.886 us; speedup 1.0000x reference)
//
#include <hip/hip_runtime.h>
#include <stdint.h>

typedef unsigned short u16;
typedef __attribute__((ext_vector_type(8))) short short8v;
typedef __attribute__((ext_vector_type(4))) short short4v;
typedef __attribute__((ext_vector_type(4))) float f32x4;

#define CC 512
#define HD 256

__device__ __forceinline__ u16 f2bf(float f) {
  union { float f; uint32_t u; } v; v.f = f;
  return (u16)((v.u + 0x7FFFu + ((v.u >> 16) & 1u)) >> 16);
}
__device__ __forceinline__ float bf2f(u16 h) {
  union { uint32_t u; float f; } v; v.u = ((uint32_t)h) << 16;
  return v.f;
}
// tanh-form gelu via HW exp2 + rcp: max abs err ~1e-3 (threshold 0.289)
__device__ __forceinline__ float gelu_c(float x) {
  float x2 = x * x;
  float a  = x * fmaf(x2, 0.044715f, 1.0f);
  float t  = __builtin_amdgcn_exp2f(a * -2.3022118f);
  return x * __builtin_amdgcn_rcpf(1.0f + t);
}

// ---------------- prep: bf16 transposed weights into ws (u16 elements) ------
//  WaT  [512][256] @ 0        (w1 rows   0..255, transposed)
//  WbT  [512][256] @ 131072   (w1 rows 256..511, transposed)
//  W2T  [256][512] @ 262144
//  U1T [1024][256] @ 393216
//  U2T  [256][1024]@ 655360
__global__ void prep_weights(const float* __restrict__ w1, const float* __restrict__ w2,
                             const float* __restrict__ u1, const float* __restrict__ u2,
                             u16* __restrict__ ws) {
  int idx = blockIdx.x * blockDim.x + threadIdx.x;
  if (idx >= 917504) return;
  float val;
  if (idx < 131072)      { int n = idx >> 8, k = idx & 255; val = w1[k * 512 + n]; }
  else if (idx < 262144) { int i = idx - 131072, n = i >> 8, k = i & 255; val = w1[(256 + k) * 512 + n]; }
  else if (idx < 393216) { int i = idx - 262144, n = i >> 9, k = i & 511; val = w2[k * 256 + n]; }
  else if (idx < 655360) { int i = idx - 393216, n = i >> 8, k = i & 255; val = u1[k * 1024 + n]; }
  else                   { int i = idx - 655360, n = i >> 10, k = i & 1023; val = u2[k * 256 + n]; }
  ws[idx] = f2bf(val);
}

// ---------------- fused kernel: msg block + update MLP ----------------------
// block = 512 thr (8 waves), grid = (32 strips, 256 batch). Strip = 16 rows,
// halo = 32. LDS = 69,440 B -> 2 blocks/CU. launch_bounds(512,4) -> <=128 VGPR.
#define SPQ 520   // u16 stride (mult of 8; 260 words mod 32 = 4-bank skew)
#define SHS 264
#define OUTS 260  // f32 stride for h_new staging
#define Q_OFF   0        // u16[32][520] = 33280 ; later sX[16][264] + sY[16][520]
#define P_OFF   33280    // u16[16][520] = 16640 ; later sOut f32[16][260] = 16640
#define H_OFF   49920    // u16[32][264] = 16896 ; later act[16][520] = 16640
#define E_OFF   66816    // 5 x f32[8][16] = 2560
#define NV_OFF  69376    // f32[16]
#define FUSED_LDS 69440

__global__ __launch_bounds__(512, 4) void fused_kernel(
    const float* __restrict__ hin, const float* __restrict__ xyz, const int* __restrict__ valid,
    const float* __restrict__ lnw, const float* __restrict__ lnb,
    const float* __restrict__ w1, const float* __restrict__ b1,
    const u16* __restrict__ WaT, const u16* __restrict__ WbT,
    const u16* __restrict__ W2T, const float* __restrict__ b2,
    const float* __restrict__ lnuw, const float* __restrict__ lnub,
    const u16* __restrict__ U1T, const float* __restrict__ bu1,
    const u16* __restrict__ U2T, const float* __restrict__ bu2,
    float* __restrict__ out) {
  extern __shared__ char lds[];
  u16* sQ   = (u16*)(lds + Q_OFF);
  u16* sP   = (u16*)(lds + P_OFF);
  u16* sH   = (u16*)(lds + H_OFF);
  u16* sAct = (u16*)(lds + H_OFF);            // overlay after phase 2
  float* sOut = (float*)(lds + P_OFF);        // overlay after phase 3
  u16* sX   = (u16*)(lds + Q_OFF);            // overlay after phase 3
  u16* sY   = (u16*)(lds + Q_OFF + 8448);     // overlay after phase 3
  float* sEx = (float*)(lds + E_OFF);         // [8][16]
  float* sEy = sEx + 128; float* sEz = sEx + 256;
  float* sEd = sEx + 384; float* sV  = sEx + 512;
  float* sNV = (float*)(lds + NV_OFF);

  const int tid  = threadIdx.x;
  const int lane = tid & 63;
  const int wid  = tid >> 6;
  const int quad = lane >> 4;
  const int l16  = lane & 15;
  const int n    = blockIdx.y;
  const int c0   = blockIdx.x * 16;
  const int k4   = lane * 4;

  // edge scalars for all 8 passes x 16 rows
  if (tid < 128) {
    const int p = tid >> 4, r = tid & 15;
    const int off = 1 << (p >> 1);
    const bool fwd = ((p & 1) == 0);
    const int c = c0 + r;
    const int other = fwd ? (c + off) : (c - off);
    const bool inb = (other >= 0) && (other < CC);
    const int oc = inb ? other : c;
    float vv = 0.f;
    if (inb && (valid[n * CC + c] != 0) && (valid[n * CC + oc] != 0)) vv = 1.f;
    const float* xo = xyz + (size_t)(n * CC + oc) * 3;
    const float* xc = xyz + (size_t)(n * CC + c) * 3;
    const float dx = xo[0] - xc[0], dy = xo[1] - xc[1], dz = xo[2] - xc[2];
    const float dist = fmaxf(sqrtf(dx*dx + dy*dy + dz*dz), 1e-6f);
    const float rin = 1.f / dist;
    sEx[tid] = dx * rin; sEy[tid] = dy * rin; sEz[tid] = dz * rin;
    sEd[tid] = dist; sV[tid] = vv;
  }

  // Phase 1: LN of 32 halo rows (c0-8 .. c0+23) -> sH bf16
  {
    const float4 lw = *(const float4*)&lnw[k4];
    const float4 lb = *(const float4*)&lnb[k4];
    for (int i = 0; i < 4; ++i) {
      const int r = wid * 4 + i;
      const int ch = c0 - 8 + r;
      float x0 = 0.f, x1 = 0.f, x2 = 0.f, x3 = 0.f;
      if (ch >= 0 && ch < CC) {
        const float* src = hin + (size_t)(n * CC + ch) * HD + k4;
        x0 = src[0]; x1 = src[1]; x2 = src[2]; x3 = src[3];
      }
      float s = x0 + x1 + x2 + x3;
      float ss = x0*x0 + x1*x1 + x2*x2 + x3*x3;
      #pragma unroll
      for (int m = 1; m < 64; m <<= 1) { s += __shfl_xor(s, m, 64); ss += __shfl_xor(ss, m, 64); }
      const float mu = s * (1.f / 256.f);
      const float rstd = rsqrtf(ss * (1.f / 256.f) - mu * mu + 1e-5f);
      short4v pk;
      ((u16*)&pk)[0] = f2bf((x0 - mu) * rstd * lw.x + lb.x);
      ((u16*)&pk)[1] = f2bf((x1 - mu) * rstd * lw.y + lb.y);
      ((u16*)&pk)[2] = f2bf((x2 - mu) * rstd * lw.z + lb.z);
      ((u16*)&pk)[3] = f2bf((x3 - mu) * rstd * lw.w + lb.w);
      *(short4v*)&sH[r * SHS + k4] = pk;
    }
  }
  __syncthreads();

  // Phase 2: P = strip@Wa + b1 (1 mtile), Q = halo@Wb (2 mtiles)
  if (tid < 16) {
    float s = 0.f;
    #pragma unroll
    for (int p = 0; p < 8; ++p) s += sV[p * 16 + tid];
    sNV[tid] = s;
  }
  for (int nt = wid; nt < 32; nt += 8) {
    const int col = nt * 16 + l16;
    short8v bw[8];
    {
      const u16* bp = WaT + (size_t)col * 256;
      #pragma unroll
      for (int ks = 0; ks < 8; ++ks) bw[ks] = *(const short8v*)(bp + ks * 32 + quad * 8);
      const u16* ar = sH + (8 + l16) * SHS;
      f32x4 acc = {0.f, 0.f, 0.f, 0.f};
      #pragma unroll
      for (int ks = 0; ks < 8; ++ks)
        acc = __builtin_amdgcn_mfma_f32_16x16x32_bf16(*(const short8v*)(ar + ks * 32 + quad * 8), bw[ks], acc, 0, 0, 0);
      const float bias = b1[col];
      #pragma unroll
      for (int r = 0; r < 4; ++r) sP[(quad * 4 + r) * SPQ + col] = f2bf(acc[r] + bias);
    }
    {
      const u16* bp = WbT + (size_t)col * 256;
      #pragma unroll
      for (int ks = 0; ks < 8; ++ks) bw[ks] = *(const short8v*)(bp + ks * 32 + quad * 8);
      #pragma unroll
      for (int mt = 0; mt < 2; ++mt) {
        const u16* ar = sH + (mt * 16 + l16) * SHS;
        f32x4 acc = {0.f, 0.f, 0.f, 0.f};
        #pragma unroll
        for (int ks = 0; ks < 8; ++ks)
          acc = __builtin_amdgcn_mfma_f32_16x16x32_bf16(*(const short8v*)(ar + ks * 32 + quad * 8), bw[ks], acc, 0, 0, 0);
        #pragma unroll
        for (int r = 0; r < 4; ++r) sQ[(mt * 16 + quad * 4 + r) * SPQ + col] = f2bf(acc[r]);
      }
    }
  }
  __syncthreads();

  // Phase 3: 8 passes; P (incl b1) and We hoisted to regs; skip invalid edges
  const int row = tid >> 5;
  const int kl  = tid & 31;
  {
    short4v pp[4];
    float4 we[4][4];   // [dim][b]
    #pragma unroll
    for (int b = 0; b < 4; ++b) pp[b] = *(const short4v*)(sP + row * SPQ + kl * 4 + b * 128);
    #pragma unroll
    for (int d = 0; d < 4; ++d)
      #pragma unroll
      for (int b = 0; b < 4; ++b)
        we[d][b] = *(const float4*)&w1[(size_t)(512 + d) * 512 + kl * 4 + b * 128];
    float accr[4][4];
    #pragma unroll
    for (int b = 0; b < 4; ++b)
      #pragma unroll
      for (int j = 0; j < 4; ++j) accr[b][j] = 0.f;

    for (int pass = 0; pass < 8; ++pass) {
      const float vv = sV[pass * 16 + row];
      if (vv != 0.f) {
        const int off = 1 << (pass >> 1);
        const int doff = (pass & 1) ? -off : off;
        const float ex = sEx[pass * 16 + row], ey = sEy[pass * 16 + row];
        const float ez = sEz[pass * 16 + row], ed = sEd[pass * 16 + row];
        const u16* qr = sQ + (row + 8 + doff) * SPQ;
        #pragma unroll
        for (int b = 0; b < 4; ++b) {
          short4v qq = *(const short4v*)(qr + kl * 4 + b * 128);
          #pragma unroll
          for (int j = 0; j < 4; ++j) {
            float et = ex * ((const float*)&we[0][b])[j];
            et = fmaf(ey, ((const float*)&we[1][b])[j], et);
            et = fmaf(ez, ((const float*)&we[2][b])[j], et);
            et = fmaf(ed, ((const float*)&we[3][b])[j], et);
            const float pre = bf2f(((const u16*)&pp[b])[j]) + bf2f(((const u16*)&qq)[j]) + et;
            accr[b][j] += gelu_c(pre);
          }
        }
      }
    }
    u16* aw = sAct + row * SPQ;
    #pragma unroll
    for (int b = 0; b < 4; ++b) {
      short4v pk;
      #pragma unroll
      for (int j = 0; j < 4; ++j) ((u16*)&pk)[j] = f2bf(accr[b][j]);
      *(short4v*)(aw + kl * 4 + b * 128) = pk;
    }
  }
  __syncthreads();

  // Phase 4: agg = act(16x512)@W2 ; h_new = h + (agg + b2*nv)*valid -> sOut
  const int nt0 = wid * 2, nt1 = wid * 2 + 1;
  {
    const u16* b0p = W2T + (size_t)(nt0 * 16 + l16) * 512;
    const u16* b1p = W2T + (size_t)(nt1 * 16 + l16) * 512;
    f32x4 a0 = {0.f, 0.f, 0.f, 0.f}, a1 = {0.f, 0.f, 0.f, 0.f};
    #pragma unroll
    for (int ks = 0; ks < 16; ++ks) {
      short8v a = *(const short8v*)(sAct + l16 * SPQ + ks * 32 + quad * 8);
      a0 = __builtin_amdgcn_mfma_f32_16x16x32_bf16(a, *(const short8v*)(b0p + ks * 32 + quad * 8), a0, 0, 0, 0);
      a1 = __builtin_amdgcn_mfma_f32_16x16x32_bf16(a, *(const short8v*)(b1p + ks * 32 + quad * 8), a1, 0, 0, 0);
    }
    #pragma unroll
    for (int t = 0; t < 2; ++t) {
      const f32x4 av = t ? a1 : a0;
      const int col = (t ? nt1 : nt0) * 16 + l16;
      const float b2v = b2[col];
      #pragma unroll
      for (int r = 0; r < 4; ++r) {
        const int rw = quad * 4 + r;
        const int gc = c0 + rw;
        const float vown = (valid[n * CC + gc] != 0) ? 1.f : 0.f;
        const float hnew = hin[(size_t)(n * CC + gc) * HD + col] + (av[r] + b2v * sNV[rw]) * vown;
        sOut[rw * OUTS + col] = hnew;
      }
    }
  }
  __syncthreads();

  // Fused update: LN(h_new) -> sX bf16
  {
    const float4 uw = *(const float4*)&lnuw[k4];
    const float4 ub = *(const float4*)&lnub[k4];
    #pragma unroll
    for (int i = 0; i < 2; ++i) {
      const int r = wid * 2 + i;
      const float4 x = *(const float4*)&sOut[r * OUTS + k4];
      float s = x.x + x.y + x.z + x.w;
      float ss = x.x*x.x + x.y*x.y + x.z*x.z + x.w*x.w;
      #pragma unroll
      for (int m = 1; m < 64; m <<= 1) { s += __shfl_xor(s, m, 64); ss += __shfl_xor(ss, m, 64); }
      const float mu = s * (1.f / 256.f);
      const float rstd = rsqrtf(ss * (1.f / 256.f) - mu * mu + 1e-5f);
      short4v pk;
      ((u16*)&pk)[0] = f2bf((x.x - mu) * rstd * uw.x + ub.x);
      ((u16*)&pk)[1] = f2bf((x.y - mu) * rstd * uw.y + ub.y);
      ((u16*)&pk)[2] = f2bf((x.z - mu) * rstd * uw.z + ub.z);
      ((u16*)&pk)[3] = f2bf((x.w - mu) * rstd * uw.w + ub.w);
      *(short4v*)&sX[r * 264 + k4] = pk;
    }
  }
  __syncthreads();

  // Update MLP: two K-halves of the 1024 hidden; GEMM2 acc held in regs
  f32x4 acc2[2];
  acc2[0] = (f32x4){0.f, 0.f, 0.f, 0.f};
  acc2[1] = (f32x4){0.f, 0.f, 0.f, 0.f};
  for (int half = 0; half < 2; ++half) {
    if (half) __syncthreads();   // GEMM2(h0) reads done before sY rewrite
    for (int j = 0; j < 4; ++j) {
      const int nt = wid + j * 8;
      const int nrow = half * 512 + nt * 16 + l16;
      short8v bw[8];
      const u16* bp = U1T + (size_t)nrow * 256;
      #pragma unroll
      for (int ks = 0; ks < 8; ++ks) bw[ks] = *(const short8v*)(bp + ks * 32 + quad * 8);
      const float bv = bu1[nrow];
      const u16* ar = sX + l16 * 264;
      f32x4 acc = {0.f, 0.f, 0.f, 0.f};
      #pragma unroll
      for (int ks = 0; ks < 8; ++ks)
        acc = __builtin_amdgcn_mfma_f32_16x16x32_bf16(*(const short8v*)(ar + ks * 32 + quad * 8), bw[ks], acc, 0, 0, 0);
      #pragma unroll
      for (int r = 0; r < 4; ++r)
        sY[(quad * 4 + r) * 520 + nt * 16 + l16] = f2bf(gelu_c(acc[r] + bv));
    }
    __syncthreads();
    const u16* c0p = U2T + (size_t)(nt0 * 16 + l16) * 1024 + half * 512;
    const u16* c1p = U2T + (size_t)(nt1 * 16 + l16) * 1024 + half * 512;
    #pragma unroll
    for (int ks = 0; ks < 16; ++ks) {
      short8v a = *(const short8v*)(sY + l16 * 520 + ks * 32 + quad * 8);
      acc2[0] = __builtin_amdgcn_mfma_f32_16x16x32_bf16(a, *(const short8v*)(c0p + ks * 32 + quad * 8), acc2[0], 0, 0, 0);
      acc2[1] = __builtin_amdgcn_mfma_f32_16x16x32_bf16(a, *(const short8v*)(c1p + ks * 32 + quad * 8), acc2[1], 0, 0, 0);
    }
  }

  // Final epilogue: out = (h_new + mlp + bu2) * valid
  #pragma unroll
  for (int t = 0; t < 2; ++t) {
    const int col = (t ? nt1 : nt0) * 16 + l16;
    const float bv = bu2[col];
    #pragma unroll
    for (int r = 0; r < 4; ++r) {
      const int rw = quad * 4 + r;
      const int gc = c0 + rw;
      const float vown = (valid[n * CC + gc] != 0) ? 1.f : 0.f;
      out[(size_t)(n * CC + gc) * HD + col] = (sOut[rw * OUTS + col] + acc2[t][r] + bv) * vown;
    }
  }
}

// ---------------- launch ----------------------------------------------------
extern "C" void kernel_launch(void* const* d_in, const int* in_sizes, int n_in,
                              void* d_out, int out_size, void* d_ws, size_t ws_size,
                              hipStream_t stream) {
  (void)in_sizes; (void)n_in; (void)out_size; (void)ws_size;
  const float* h     = (const float*)d_in[0];
  const float* xyz   = (const float*)d_in[1];
  const int*   valid = (const int*)d_in[2];
  const float* lnnw  = (const float*)d_in[3];
  const float* lnnb  = (const float*)d_in[4];
  const float* w1    = (const float*)d_in[5];
  const float* b1    = (const float*)d_in[6];
  const float* w2    = (const float*)d_in[7];
  const float* b2    = (const float*)d_in[8];
  const float* lnuw  = (const float*)d_in[9];
  const float* lnub  = (const float*)d_in[10];
  const float* u1    = (const float*)d_in[11];
  const float* bu1   = (const float*)d_in[12];
  const float* u2    = (const float*)d_in[13];
  const float* bu2   = (const float*)d_in[14];
  float* out = (float*)d_out;
  u16* ws = (u16*)d_ws;

  hipFuncSetAttribute(reinterpret_cast<const void*>(fused_kernel),
                      hipFuncAttributeMaxDynamicSharedMemorySize, FUSED_LDS);

  prep_weights<<<dim3(3584), dim3(256), 0, stream>>>(w1, w2, u1, u2, ws);
  fused_kernel<<<dim3(32, 256), dim3(512), FUSED_LDS, stream>>>(
      h, xyz, valid, lnnw, lnnb, w1, b1,
      ws, ws + 131072, ws + 262144, b2,
      lnuw, lnub, ws + 393216, bu1, ws + 655360, bu2, out);
}

// Round 4
// 1449.477 us; speedup vs baseline: 1.3604x; 1.3604x over previous
//
#include <hip/hip_runtime.h>
#include <stdint.h>

typedef unsigned short u16;
typedef __attribute__((ext_vector_type(8))) short short8v;
typedef __attribute__((ext_vector_type(4))) short short4v;
typedef __attribute__((ext_vector_type(4))) float f32x4;

#define CC 512
#define HD 256

__device__ __forceinline__ u16 f2bf(float f) {
  union { float f; uint32_t u; } v; v.f = f;
  return (u16)((v.u + 0x7FFFu + ((v.u >> 16) & 1u)) >> 16);
}
__device__ __forceinline__ float bf2f(u16 h) {
  union { uint32_t u; float f; } v; v.u = ((uint32_t)h) << 16;
  return v.f;
}
// tanh-form gelu via HW exp2 + rcp: max abs err ~1e-3 (threshold 0.289)
__device__ __forceinline__ float gelu_c(float x) {
  float x2 = x * x;
  float a  = x * fmaf(x2, 0.044715f, 1.0f);
  float t  = __builtin_amdgcn_exp2f(a * -2.3022118f);
  return x * __builtin_amdgcn_rcpf(1.0f + t);
}

// ---------------- prep: bf16 transposed weights into ws (u16 elements) ------
//  WaT  [512][256] @ 0        (w1 rows   0..255, transposed)
//  WbT  [512][256] @ 131072   (w1 rows 256..511, transposed)
//  W2T  [256][512] @ 262144
//  U1T [1024][256] @ 393216
//  U2T  [256][1024]@ 655360
__global__ void prep_weights(const float* __restrict__ w1, const float* __restrict__ w2,
                             const float* __restrict__ u1, const float* __restrict__ u2,
                             u16* __restrict__ ws) {
  int idx = blockIdx.x * blockDim.x + threadIdx.x;
  if (idx >= 917504) return;
  float val;
  if (idx < 131072)      { int n = idx >> 8, k = idx & 255; val = w1[k * 512 + n]; }
  else if (idx < 262144) { int i = idx - 131072, n = i >> 8, k = i & 255; val = w1[(256 + k) * 512 + n]; }
  else if (idx < 393216) { int i = idx - 262144, n = i >> 9, k = i & 511; val = w2[k * 256 + n]; }
  else if (idx < 655360) { int i = idx - 393216, n = i >> 8, k = i & 255; val = u1[k * 1024 + n]; }
  else                   { int i = idx - 655360, n = i >> 10, k = i & 1023; val = u2[k * 256 + n]; }
  ws[idx] = f2bf(val);
}

// ---------------- strip kernel: 16-row strips, 32-row halo ------------------
// block = 512 thr (8 waves), grid = (32 strips, 256 batch).
// LDS = 52,800 B -> 3 blocks/CU (24 waves, 75% occ). launch_bounds(512,6) -> <=85 VGPR.
// P lives entirely in registers (MFMA C-layout ownership carried into phase 3).
#define SPQ 520   // u16 stride
#define SHS 264
#define Q_OFF   0        // u16[32][520] = 33280
#define H_OFF   33280    // u16[32][264] = 16896 ; act u16[16][520]=16640 overlays
#define E_OFF   50176    // 5 x f32[8][16] = 2560
#define NV_OFF  52736    // f32[16]
#define STRIP_LDS 52800

__global__ __launch_bounds__(512, 6) void strip_kernel(
    const float* __restrict__ hin, const float* __restrict__ xyz, const int* __restrict__ valid,
    const float* __restrict__ lnw, const float* __restrict__ lnb,
    const float* __restrict__ w1, const float* __restrict__ b1,
    const u16* __restrict__ WaT, const u16* __restrict__ WbT,
    const u16* __restrict__ W2T, const float* __restrict__ b2,
    float* __restrict__ out) {
  extern __shared__ char lds[];
  u16* sQ   = (u16*)(lds + Q_OFF);
  u16* sH   = (u16*)(lds + H_OFF);
  u16* sAct = (u16*)(lds + H_OFF);          // overlay after phase 2
  float* sEx = (float*)(lds + E_OFF);       // [8][16]
  float* sEy = sEx + 128; float* sEz = sEx + 256;
  float* sEd = sEx + 384; float* sV  = sEx + 512;
  float* sNV = (float*)(lds + NV_OFF);

  const int tid  = threadIdx.x;
  const int lane = tid & 63;
  const int wid  = tid >> 6;
  const int quad = lane >> 4;
  const int l16  = lane & 15;
  const int n    = blockIdx.y;
  const int c0   = blockIdx.x * 16;
  const int k4   = lane * 4;

  // edge scalars for all 8 passes x 16 rows
  if (tid < 128) {
    const int p = tid >> 4, r = tid & 15;
    const int off = 1 << (p >> 1);
    const bool fwd = ((p & 1) == 0);
    const int c = c0 + r;
    const int other = fwd ? (c + off) : (c - off);
    const bool inb = (other >= 0) && (other < CC);
    const int oc = inb ? other : c;
    float vv = 0.f;
    if (inb && (valid[n * CC + c] != 0) && (valid[n * CC + oc] != 0)) vv = 1.f;
    const float* xo = xyz + (size_t)(n * CC + oc) * 3;
    const float* xc = xyz + (size_t)(n * CC + c) * 3;
    const float dx = xo[0] - xc[0], dy = xo[1] - xc[1], dz = xo[2] - xc[2];
    const float dist = fmaxf(sqrtf(dx*dx + dy*dy + dz*dz), 1e-6f);
    const float rin = 1.f / dist;
    sEx[tid] = dx * rin; sEy[tid] = dy * rin; sEz[tid] = dz * rin;
    sEd[tid] = dist; sV[tid] = vv;
  }

  // Phase 1: LN of 32 halo rows (c0-8 .. c0+23) -> sH bf16 (4 rows/wave)
  {
    const float4 lw = *(const float4*)&lnw[k4];
    const float4 lb = *(const float4*)&lnb[k4];
    for (int i = 0; i < 4; ++i) {
      const int r = wid * 4 + i;
      const int ch = c0 - 8 + r;
      float x0 = 0.f, x1 = 0.f, x2 = 0.f, x3 = 0.f;
      if (ch >= 0 && ch < CC) {
        const float* src = hin + (size_t)(n * CC + ch) * HD + k4;
        x0 = src[0]; x1 = src[1]; x2 = src[2]; x3 = src[3];
      }
      float s = x0 + x1 + x2 + x3;
      float ss = x0*x0 + x1*x1 + x2*x2 + x3*x3;
      #pragma unroll
      for (int m = 1; m < 64; m <<= 1) { s += __shfl_xor(s, m, 64); ss += __shfl_xor(ss, m, 64); }
      const float mu = s * (1.f / 256.f);
      const float rstd = rsqrtf(ss * (1.f / 256.f) - mu * mu + 1e-5f);
      short4v pk;
      ((u16*)&pk)[0] = f2bf((x0 - mu) * rstd * lw.x + lb.x);
      ((u16*)&pk)[1] = f2bf((x1 - mu) * rstd * lw.y + lb.y);
      ((u16*)&pk)[2] = f2bf((x2 - mu) * rstd * lw.z + lb.z);
      ((u16*)&pk)[3] = f2bf((x3 - mu) * rstd * lw.w + lb.w);
      *(short4v*)&sH[r * SHS + k4] = pk;
    }
  }
  __syncthreads();

  if (tid < 16) {
    float s = 0.f;
    #pragma unroll
    for (int p = 0; p < 8; ++p) s += sV[p * 16 + tid];
    sNV[tid] = s;
  }

  // Phase 2: P (regs, +b1) and Q (LDS). Thread col_j = (wid + j*8)*16 + l16.
  float pAcc[4][4];   // [j][r]: P[row=quad*4+r][col_j] + b1
  #pragma unroll
  for (int j = 0; j < 4; ++j) {
    const int nt = wid + j * 8;
    const int col = nt * 16 + l16;
    short8v bw[8];
    {
      const u16* bp = WaT + (size_t)col * 256;
      #pragma unroll
      for (int ks = 0; ks < 8; ++ks) bw[ks] = *(const short8v*)(bp + ks * 32 + quad * 8);
      const u16* ar = sH + (8 + l16) * SHS;
      f32x4 acc = {0.f, 0.f, 0.f, 0.f};
      #pragma unroll
      for (int ks = 0; ks < 8; ++ks)
        acc = __builtin_amdgcn_mfma_f32_16x16x32_bf16(*(const short8v*)(ar + ks * 32 + quad * 8), bw[ks], acc, 0, 0, 0);
      const float bias = b1[col];
      #pragma unroll
      for (int r = 0; r < 4; ++r) pAcc[j][r] = acc[r] + bias;
    }
    {
      const u16* bp = WbT + (size_t)col * 256;
      #pragma unroll
      for (int ks = 0; ks < 8; ++ks) bw[ks] = *(const short8v*)(bp + ks * 32 + quad * 8);
      #pragma unroll
      for (int mt = 0; mt < 2; ++mt) {
        const u16* ar = sH + (mt * 16 + l16) * SHS;
        f32x4 acc = {0.f, 0.f, 0.f, 0.f};
        #pragma unroll
        for (int ks = 0; ks < 8; ++ks)
          acc = __builtin_amdgcn_mfma_f32_16x16x32_bf16(*(const short8v*)(ar + ks * 32 + quad * 8), bw[ks], acc, 0, 0, 0);
        #pragma unroll
        for (int r = 0; r < 4; ++r) sQ[(mt * 16 + quad * 4 + r) * SPQ + col] = f2bf(acc[r]);
      }
    }
  }
  // edge-weight cols for this thread's 4 cols (global, read-once)
  float we[4][4];   // [d][j]
  #pragma unroll
  for (int d = 0; d < 4; ++d)
    #pragma unroll
    for (int j = 0; j < 4; ++j)
      we[d][j] = w1[(size_t)(512 + d) * 512 + (wid + j * 8) * 16 + l16];
  __syncthreads();

  // Phase 3: 8 passes in C-layout ownership: rows quad*4+r, cols col_j
  float accr[4][4];   // [j][r]
  #pragma unroll
  for (int j = 0; j < 4; ++j)
    #pragma unroll
    for (int r = 0; r < 4; ++r) accr[j][r] = 0.f;

  for (int pass = 0; pass < 8; ++pass) {
    float vvr[4];
    #pragma unroll
    for (int r = 0; r < 4; ++r) vvr[r] = sV[pass * 16 + quad * 4 + r];
    if (vvr[0] + vvr[1] + vvr[2] + vvr[3] != 0.f) {
      const int off = 1 << (pass >> 1);
      const int doff = (pass & 1) ? -off : off;
      #pragma unroll
      for (int r = 0; r < 4; ++r) {
        if (vvr[r] != 0.f) {
          const int row = quad * 4 + r;
          const float ex = sEx[pass * 16 + row], ey = sEy[pass * 16 + row];
          const float ez = sEz[pass * 16 + row], ed = sEd[pass * 16 + row];
          const u16* qr = sQ + (row + 8 + doff) * SPQ;
          #pragma unroll
          for (int j = 0; j < 4; ++j) {
            const int col = (wid + j * 8) * 16 + l16;
            float et = ex * we[0][j];
            et = fmaf(ey, we[1][j], et);
            et = fmaf(ez, we[2][j], et);
            et = fmaf(ed, we[3][j], et);
            const float pre = pAcc[j][r] + bf2f(qr[col]) + et;
            accr[j][r] += gelu_c(pre);
          }
        }
      }
    }
  }
  // write act (overlays sH; sH reads all completed before prior barrier)
  #pragma unroll
  for (int r = 0; r < 4; ++r) {
    u16* aw = sAct + (quad * 4 + r) * SPQ;
    #pragma unroll
    for (int j = 0; j < 4; ++j)
      aw[(wid + j * 8) * 16 + l16] = f2bf(accr[j][r]);
  }
  __syncthreads();

  // Phase 4: agg = act(16x512)@W2 ; out = h + (agg + b2*nv)*valid
  {
    const int nt0 = wid * 2, nt1 = wid * 2 + 1;
    const u16* b0p = W2T + (size_t)(nt0 * 16 + l16) * 512;
    const u16* b1p = W2T + (size_t)(nt1 * 16 + l16) * 512;
    f32x4 a0 = {0.f, 0.f, 0.f, 0.f}, a1 = {0.f, 0.f, 0.f, 0.f};
    #pragma unroll
    for (int ks = 0; ks < 16; ++ks) {
      short8v a = *(const short8v*)(sAct + l16 * SPQ + ks * 32 + quad * 8);
      a0 = __builtin_amdgcn_mfma_f32_16x16x32_bf16(a, *(const short8v*)(b0p + ks * 32 + quad * 8), a0, 0, 0, 0);
      a1 = __builtin_amdgcn_mfma_f32_16x16x32_bf16(a, *(const short8v*)(b1p + ks * 32 + quad * 8), a1, 0, 0, 0);
    }
    #pragma unroll
    for (int t = 0; t < 2; ++t) {
      const f32x4 av = t ? a1 : a0;
      const int col = (t ? nt1 : nt0) * 16 + l16;
      const float b2v = b2[col];
      #pragma unroll
      for (int r = 0; r < 4; ++r) {
        const int rw = quad * 4 + r;
        const int gc = c0 + rw;
        const float vown = (valid[n * CC + gc] != 0) ? 1.f : 0.f;
        const size_t gi = (size_t)(n * CC + gc) * HD + col;
        out[gi] = hin[gi] + (av[r] + b2v * sNV[rw]) * vown;
      }
    }
  }
}

// ---------------- update kernel: LN -> 256->1024 gelu -> 1024->256 ----------
// M=32 rows/block; hidden processed in four 256-wide quarters with GEMM2
// accumulators register-resident. LDS = 33,792 B -> 4 blocks/CU (32 waves).
#define X_S 264
#define Y_S 264
#define UX_OFF 0          // u16[32][264] = 16896
#define UY_OFF 16896      // u16[32][264] = 16896
#define UPD_LDS 33792

__global__ __launch_bounds__(512, 8) void update_kernel(
    const float* __restrict__ lnw, const float* __restrict__ lnb,
    const u16* __restrict__ U1T, const float* __restrict__ bu1,
    const u16* __restrict__ U2T, const float* __restrict__ bu2,
    const int* __restrict__ valid, float* __restrict__ out) {
  extern __shared__ char lds[];
  u16* sX = (u16*)(lds + UX_OFF);
  u16* sY = (u16*)(lds + UY_OFF);

  const int tid  = threadIdx.x;
  const int lane = tid & 63;
  const int wid  = tid >> 6;
  const int quad = lane >> 4;
  const int l16  = lane & 15;
  const int n    = blockIdx.y;
  const int c0   = blockIdx.x * 32;
  const int k4   = lane * 4;

  // Phase A: LN(out rows) -> sX bf16
  {
    const float4 lw = *(const float4*)&lnw[k4];
    const float4 lb = *(const float4*)&lnb[k4];
    for (int i = 0; i < 4; ++i) {
      const int r = wid * 4 + i;
      const float* src = out + (size_t)(n * CC + c0 + r) * HD + k4;
      const float x0 = src[0], x1 = src[1], x2 = src[2], x3 = src[3];
      float s = x0 + x1 + x2 + x3;
      float ss = x0*x0 + x1*x1 + x2*x2 + x3*x3;
      #pragma unroll
      for (int m = 1; m < 64; m <<= 1) { s += __shfl_xor(s, m, 64); ss += __shfl_xor(ss, m, 64); }
      const float mu = s * (1.f / 256.f);
      const float rstd = rsqrtf(ss * (1.f / 256.f) - mu * mu + 1e-5f);
      short4v pk;
      ((u16*)&pk)[0] = f2bf((x0 - mu) * rstd * lw.x + lb.x);
      ((u16*)&pk)[1] = f2bf((x1 - mu) * rstd * lw.y + lb.y);
      ((u16*)&pk)[2] = f2bf((x2 - mu) * rstd * lw.z + lb.z);
      ((u16*)&pk)[3] = f2bf((x3 - mu) * rstd * lw.w + lb.w);
      *(short4v*)&sX[r * X_S + k4] = pk;
    }
  }
  __syncthreads();

  // Quartered hidden: GEMM2 acc held in regs across quarters.
  f32x4 acc2[4];   // [t*2 + mt]
  #pragma unroll
  for (int i = 0; i < 4; ++i) acc2[i] = (f32x4){0.f, 0.f, 0.f, 0.f};

  for (int q = 0; q < 4; ++q) {
    if (q) __syncthreads();   // prior GEMM2 reads of sY done before overwrite
    // GEMM1 quarter: y_q = gelu(X @ U1[:, q*256 .. +256) + bu1)
    #pragma unroll
    for (int t = 0; t < 2; ++t) {
      const int nt = wid * 2 + t;
      const int nrow = q * 256 + nt * 16 + l16;
      short8v bw[8];
      const u16* bp = U1T + (size_t)nrow * 256;
      #pragma unroll
      for (int ks = 0; ks < 8; ++ks) bw[ks] = *(const short8v*)(bp + ks * 32 + quad * 8);
      const float bv = bu1[nrow];
      #pragma unroll
      for (int mt = 0; mt < 2; ++mt) {
        const u16* ar = sX + (mt * 16 + l16) * X_S;
        f32x4 acc = {0.f, 0.f, 0.f, 0.f};
        #pragma unroll
        for (int ks = 0; ks < 8; ++ks)
          acc = __builtin_amdgcn_mfma_f32_16x16x32_bf16(*(const short8v*)(ar + ks * 32 + quad * 8), bw[ks], acc, 0, 0, 0);
        #pragma unroll
        for (int r = 0; r < 4; ++r)
          sY[(mt * 16 + quad * 4 + r) * Y_S + nt * 16 + l16] = f2bf(gelu_c(acc[r] + bv));
      }
    }
    __syncthreads();
    // GEMM2 partial: acc2 += y_q @ U2[q*256 .. , :]
    #pragma unroll
    for (int t = 0; t < 2; ++t) {
      const int nt = wid * 2 + t;
      short8v cw[8];
      const u16* cp = U2T + (size_t)(nt * 16 + l16) * 1024 + q * 256;
      #pragma unroll
      for (int ks = 0; ks < 8; ++ks) cw[ks] = *(const short8v*)(cp + ks * 32 + quad * 8);
      #pragma unroll
      for (int mt = 0; mt < 2; ++mt) {
        const u16* ar = sY + (mt * 16 + l16) * Y_S;
        #pragma unroll
        for (int ks = 0; ks < 8; ++ks)
          acc2[t * 2 + mt] = __builtin_amdgcn_mfma_f32_16x16x32_bf16(*(const short8v*)(ar + ks * 32 + quad * 8), cw[ks], acc2[t * 2 + mt], 0, 0, 0);
      }
    }
  }

  // Epilogue: out = (h_new + mlp + bu2) * valid   (h_new re-read; L1/L2 hit)
  #pragma unroll
  for (int t = 0; t < 2; ++t) {
    const int col = (wid * 2 + t) * 16 + l16;
    const float bv = bu2[col];
    #pragma unroll
    for (int mt = 0; mt < 2; ++mt) {
      #pragma unroll
      for (int r = 0; r < 4; ++r) {
        const int rw = mt * 16 + quad * 4 + r;
        const int gc = c0 + rw;
        const float vown = (valid[n * CC + gc] != 0) ? 1.f : 0.f;
        const size_t gi = (size_t)(n * CC + gc) * HD + col;
        out[gi] = (out[gi] + acc2[t * 2 + mt][r] + bv) * vown;
      }
    }
  }
}

// ---------------- launch ----------------------------------------------------
extern "C" void kernel_launch(void* const* d_in, const int* in_sizes, int n_in,
                              void* d_out, int out_size, void* d_ws, size_t ws_size,
                              hipStream_t stream) {
  (void)in_sizes; (void)n_in; (void)out_size; (void)ws_size;
  const float* h     = (const float*)d_in[0];
  const float* xyz   = (const float*)d_in[1];
  const int*   valid = (const int*)d_in[2];
  const float* lnnw  = (const float*)d_in[3];
  const float* lnnb  = (const float*)d_in[4];
  const float* w1    = (const float*)d_in[5];
  const float* b1    = (const float*)d_in[6];
  const float* w2    = (const float*)d_in[7];
  const float* b2    = (const float*)d_in[8];
  const float* lnuw  = (const float*)d_in[9];
  const float* lnub  = (const float*)d_in[10];
  const float* u1    = (const float*)d_in[11];
  const float* bu1   = (const float*)d_in[12];
  const float* u2    = (const float*)d_in[13];
  const float* bu2   = (const float*)d_in[14];
  float* out = (float*)d_out;
  u16* ws = (u16*)d_ws;

  hipFuncSetAttribute(reinterpret_cast<const void*>(strip_kernel),
                      hipFuncAttributeMaxDynamicSharedMemorySize, STRIP_LDS);
  hipFuncSetAttribute(reinterpret_cast<const void*>(update_kernel),
                      hipFuncAttributeMaxDynamicSharedMemorySize, UPD_LDS);

  prep_weights<<<dim3(3584), dim3(256), 0, stream>>>(w1, w2, u1, u2, ws);
  strip_kernel<<<dim3(32, 256), dim3(512), STRIP_LDS, stream>>>(
      h, xyz, valid, lnnw, lnnb, w1, b1,
      ws, ws + 131072, ws + 262144, b2, out);
  update_kernel<<<dim3(16, 256), dim3(512), UPD_LDS, stream>>>(
      lnuw, lnub, ws + 393216, bu1, ws + 655360, bu2, valid, out);
}